// Round 12
// baseline (184.042 us; speedup 1.0000x reference)
//
#include <hip/hip_runtime.h>
#include <math.h>

#ifndef __has_builtin
#define __has_builtin(x) 0
#endif

#define NPTS   131072
#define FCH    16
#define CSND   343.0f
#define PB     16           // points per pass
#define BLOCK  256          // 4 waves
#define GRID   2048         // 4 passes/WG; backfill gives cross-WG phase diversity
#define NBLK   (NPTS / PB)  // 8192

typedef _Float16 half8 __attribute__((ext_vector_type(8)));
typedef _Float16 half2v __attribute__((ext_vector_type(2)));
typedef float    f32x4 __attribute__((ext_vector_type(4)));

static __device__ __forceinline__ half2v pk2h(float a, float b) {
#if __has_builtin(__builtin_amdgcn_cvt_pkrtz)
  return __builtin_bit_cast(half2v, __builtin_amdgcn_cvt_pkrtz(a, b));
#else
  half2v v; v[0] = (_Float16)a; v[1] = (_Float16)b;
  return v;
#endif
}
static __device__ __forceinline__ unsigned pack2(float a, float b) {
  return __builtin_bit_cast(unsigned, pk2h(a, b));
}
#define U32(h) __builtin_bit_cast(unsigned, (h))

// tanh(x) = 1 - 2/(e^{2x}+1): exp+rcp on trans pipe, monotone at +/-inf.
static __device__ __forceinline__ float mytanh(float x) {
#if __has_builtin(__builtin_amdgcn_exp2f)
  float e = __builtin_amdgcn_exp2f(2.885390082f * x);   // 2*log2(e)*x
#else
  float e = __expf(2.0f * x);
#endif
  return fmaf(-2.0f, __builtin_amdgcn_rcpf(e + 1.0f), 1.0f);
}

// THE UNTRIED MATRIX CELL: R10's 28KB 2-barrier kernel with bounds(256,3).
// Evidence chain:
//  - R10 ((256,4), 28KB): occupancy 34.7% -- residency DOES follow LDS math --
//    but the 128-reg hard cap forced a spill storm (WRITE 104MB). 3rd strike
//    for (256,4); never again.
//  - R11 ((256,3)): this phase-distribution body allocates at 84 VGPR under
//    the ~170 cap -- comfortably under the 102-reg/5-wave threshold.
//  - Residency = min(LDS-limit, 512/actual-VGPR); launch_bounds only caps the
//    allocator. 28KB -> 5 WG/CU; VGPR<=102 -> 5 waves/EU  =>  5 resident WGs,
//    2.5x the best clean config, with zero spill pressure.
// Structure (R6's proven 2-barrier skeleton at PB=16, phases == R9/R10):
//   [D(i-1) rd HG; A(i) wr s_A] |b1| [loadX(i+1); B(i) rd s_A; C(i) wr HG] |b2|
// Hazards: D rd HG vs C wr HG across b1; A wr s_A vs B(i-1) rd across b2;
// B rd s_A vs A(i) wr same-iteration ordered by b1.
// Phases (PB=16, 4 waves): A: 1pt/thread (pA=tid>>4), packed-f16, 5x b128 wr.
// B: wave w owns n-quarter (cols 32w+16nt+col), 20 ds_read + 40 MFMA, per-d
// accd collapse. C: q=16w+col paired-dword -> HG (chunk-swizzle (q>>2)^p).
// D: waves 0/1 (nh=w&1), 16 MFMA; w3f j-perm j = 32ks+16(j8&1)+4quad+(j8>>1).
// LDS: s_A[80][64] dw (20KB): rows R=v*16+p (v=0..4: h1,d0,d1,d2,c1), chunk c
// at (c ^ p). s_HG[16][128] dw (8KB): point p: h2 [0..63], G [64..127].

__global__ __launch_bounds__(BLOCK, 3) void helmholtz_kernel(
    const float* __restrict__ x,      // [N,3]
    const float* __restrict__ omega,  // [16]
    const float* __restrict__ W1,     // [3,128]
    const float* __restrict__ b1,     // [128]
    const float* __restrict__ W2,     // [128,128]
    const float* __restrict__ b2,     // [128]
    const float* __restrict__ W3,     // [128,32]
    const float* __restrict__ b3,     // [32]
    float* __restrict__ out)
{
  __shared__ unsigned s_A[80 * 64];    // 20 KB
  __shared__ unsigned s_HG[16 * 128];  // 8 KB   (28 KB total -> 5 WG/CU by LDS)

  const int tid  = threadIdx.x;
  const int w    = tid >> 6;   // wave 0..3
  const int l    = tid & 63;
  const int col  = l & 15;
  const int quad = l >> 4;
  const int nh   = w & 1;      // D re/im tile (waves 0/1)

  // ---- phase A task: point pA (one per thread); units 8g..8g+7 ----
  const int pA = tid >> 4;     // 0..15
  const int g  = tid & 15;
  float wx[8], wy[8], wz[8], bB[8];
#pragma unroll
  for (int u = 0; u < 8; u++) {
    int unit = 8 * g + u;
    wx[u] = W1[unit]; wy[u] = W1[128 + unit]; wz[u] = W1[256 + unit];
    bB[u] = b1[unit];
  }
  // packed W1 copies + folded -2*wq (computed once)
  half2v wxp[4], wyp[4], wzp[4], wqm[4];
#pragma unroll
  for (int j = 0; j < 4; j++) {
    wxp[j] = pk2h(wx[2*j], wx[2*j+1]);
    wyp[j] = pk2h(wy[2*j], wy[2*j+1]);
    wzp[j] = pk2h(wz[2*j], wz[2*j+1]);
    float wq0 = fmaf(wx[2*j],   wx[2*j],   fmaf(wy[2*j],   wy[2*j],   wz[2*j]   * wz[2*j]));
    float wq1 = fmaf(wx[2*j+1], wx[2*j+1], fmaf(wy[2*j+1], wy[2*j+1], wz[2*j+1] * wz[2*j+1]));
    wqm[j] = pk2h(-2.0f * wq0, -2.0f * wq1);
  }
  const half2v hone = {(_Float16)1.0f, (_Float16)1.0f};

  // ---- W2^T fragments: 2 n-tiles (cols 32*w + 16*nt + col), 32 VGPRs ----
  half8 w2f[2][4];
#pragma unroll
  for (int nt = 0; nt < 2; nt++) {
    const int n = 32 * w + 16 * nt + col;
#pragma unroll
    for (int ks = 0; ks < 4; ks++) {
      half8 f;
#pragma unroll
      for (int j8 = 0; j8 < 8; j8++)
        f[j8] = (_Float16)W2[(ks * 32 + (quad << 3) + j8) * 128 + n];
      w2f[nt][ks] = f;
    }
  }
  // ---- W3^T fragment, j-permuted to match HG layout (16 VGPRs) ----
  half8 w3f[4];
#pragma unroll
  for (int ks = 0; ks < 4; ks++) {
    half8 f;
#pragma unroll
    for (int j8 = 0; j8 < 8; j8++) {
      int j = 32 * ks + 16 * (j8 & 1) + 4 * quad + (j8 >> 1);
      f[j8] = (_Float16)W3[j * 32 + 16 * nh + col];
    }
    w3f[ks] = f;
  }

  float b2r[2];
#pragma unroll
  for (int nt = 0; nt < 2; nt++) b2r[nt] = b2[32 * w + 16 * nt + col];
  float k2v = 0.0f;
  if (col >= 1) {
    float om = omega[col] * (1.0f / CSND);
    k2v = om * om;
  }
  const float b3v = b3[16 * nh + col];

  float wsum = 0.0f;
  float xr[3];

  auto loadX = [&](int blk) {
    const float* xb = x + (size_t)blk * PB * 3;
    xr[0] = xb[3 * pA]; xr[1] = xb[3 * pA + 1]; xr[2] = xb[3 * pA + 2];
  };

  auto phaseA = [&]() {
    const int cbase = (g ^ pA) << 2;
    float x0 = xr[0], x1 = xr[1], x2 = xr[2];
    float t[8];
#pragma unroll
    for (int u = 0; u < 8; u++) {
      float z = fmaf(x0, wx[u], fmaf(x1, wy[u], fmaf(x2, wz[u], bB[u])));
      t[u] = mytanh(z);
    }
    half2v tp[4], sp[4];
#pragma unroll
    for (int j = 0; j < 4; j++) {
      tp[j] = pk2h(t[2*j], t[2*j+1]);
      sp[j] = hone - tp[j] * tp[j];
    }
    uint4 q;
    q = make_uint4(U32(tp[0]), U32(tp[1]), U32(tp[2]), U32(tp[3]));
    *(uint4*)&s_A[(pA)      * 64 + cbase] = q;
    q = make_uint4(U32(sp[0]*wxp[0]), U32(sp[1]*wxp[1]),
                   U32(sp[2]*wxp[2]), U32(sp[3]*wxp[3]));
    *(uint4*)&s_A[(16 + pA) * 64 + cbase] = q;
    q = make_uint4(U32(sp[0]*wyp[0]), U32(sp[1]*wyp[1]),
                   U32(sp[2]*wyp[2]), U32(sp[3]*wyp[3]));
    *(uint4*)&s_A[(32 + pA) * 64 + cbase] = q;
    q = make_uint4(U32(sp[0]*wzp[0]), U32(sp[1]*wzp[1]),
                   U32(sp[2]*wzp[2]), U32(sp[3]*wzp[3]));
    *(uint4*)&s_A[(48 + pA) * 64 + cbase] = q;
    half2v cp[4];
#pragma unroll
    for (int j = 0; j < 4; j++) cp[j] = (tp[j] * sp[j]) * wqm[j];
    q = make_uint4(U32(cp[0]), U32(cp[1]), U32(cp[2]), U32(cp[3]));
    *(uint4*)&s_A[(64 + pA) * 64 + cbase] = q;
  };

  auto phaseD = [&]() {
    if (w < 2) {
      const int pbase = col * 128;   // row = col; swizzle key col
      f32x4 dy = (f32x4){0.0f, 0.0f, 0.0f, 0.0f};
      f32x4 dl = (f32x4){0.0f, 0.0f, 0.0f, 0.0f};
#pragma unroll
      for (int ks = 0; ks < 4; ks++) {
        int pos = ((((ks << 2) + quad) ^ col) << 2);
        half8 afy = *(const half8*)&s_HG[pbase + pos];
        half8 afl = *(const half8*)&s_HG[pbase + 64 + pos];
        dy = __builtin_amdgcn_mfma_f32_16x16x32_f16(afy, w3f[ks], dy, 0, 0, 0);
        dl = __builtin_amdgcn_mfma_f32_16x16x32_f16(afl, w3f[ks], dl, 0, 0, 0);
      }
      if (col >= 1) {
#pragma unroll
        for (int r = 0; r < 4; r++) {
          float yv  = dy[r] + b3v;
          float res = fmaf(k2v, yv, dl[r]);
          wsum += res * res;
        }
      }
    }
  };

  // ---- main loop: [D(i-1); A(i)] |b1| [loadX; B(i); C(i)] |b2| ----
  loadX(blockIdx.x);
  bool first = true;
  for (int blk = blockIdx.x; blk < NBLK; blk += GRID) {
    if (!first) phaseD();           // D(i-1): reads s_HG
    first = false;
    phaseA();                       // A(i): writes s_A
    __syncthreads();                // b1

    int nblk = blk + GRID;
    if (nblk < NBLK) loadX(nblk);   // prefetch x for next pass

    // ---- B(i): m16 x n-quarter GEMM; per-d collapse caps transients ----
    f32x4 bsum[2], acch[2], accc[2];
#pragma unroll
    for (int nt = 0; nt < 2; nt++)
      bsum[nt] = (f32x4){0.0f, 0.0f, 0.0f, 0.0f};
#pragma unroll
    for (int d = 0; d < 3; d++) {
      f32x4 accd[2];
#pragma unroll
      for (int nt = 0; nt < 2; nt++)
        accd[nt] = (f32x4){0.0f, 0.0f, 0.0f, 0.0f};
      const int rb = ((d + 1) * 16 + col) * 64;
#pragma unroll
      for (int ks = 0; ks < 4; ks++) {
        half8 af = *(const half8*)&s_A[rb + ((((ks << 2) + quad) ^ col) << 2)];
        accd[0] = __builtin_amdgcn_mfma_f32_16x16x32_f16(af, w2f[0][ks], accd[0], 0, 0, 0);
        accd[1] = __builtin_amdgcn_mfma_f32_16x16x32_f16(af, w2f[1][ks], accd[1], 0, 0, 0);
      }
#pragma unroll
      for (int nt = 0; nt < 2; nt++)
        bsum[nt] += accd[nt] * accd[nt];
    }
#pragma unroll
    for (int nt = 0; nt < 2; nt++) {
      acch[nt] = (f32x4){0.0f, 0.0f, 0.0f, 0.0f};
      accc[nt] = (f32x4){0.0f, 0.0f, 0.0f, 0.0f};
    }
    {
      const int rb0 = (col) * 64;        // h1 rows (v=0)
      const int rb4 = (64 + col) * 64;   // c1 rows (v=4)
#pragma unroll
      for (int ks = 0; ks < 4; ks++) {
        int pos = ((((ks << 2) + quad) ^ col) << 2);
        half8 afh = *(const half8*)&s_A[rb0 + pos];
        half8 afc = *(const half8*)&s_A[rb4 + pos];
        acch[0] = __builtin_amdgcn_mfma_f32_16x16x32_f16(afh, w2f[0][ks], acch[0], 0, 0, 0);
        acch[1] = __builtin_amdgcn_mfma_f32_16x16x32_f16(afh, w2f[1][ks], acch[1], 0, 0, 0);
        accc[0] = __builtin_amdgcn_mfma_f32_16x16x32_f16(afc, w2f[0][ks], accc[0], 0, 0, 0);
        accc[1] = __builtin_amdgcn_mfma_f32_16x16x32_f16(afc, w2f[1][ks], accc[1], 0, 0, 0);
      }
    }

    // ---- C(i): layer-2 elementwise -> s_HG (q = 16w+col) ----
    {
      const int q  = 16 * w + col;
      const int qc = q >> 2, qr = q & 3;
#pragma unroll
      for (int r = 0; r < 4; r++) {
        int p = (quad << 2) + r;             // point 0..15
        float t2[2], gg[2];
#pragma unroll
        for (int nt = 0; nt < 2; nt++) {
          float z2 = acch[nt][r] + b2r[nt];
          float t  = mytanh(z2);
          float s2 = 1.0f - t * t;
          t2[nt] = t;
          gg[nt] = s2 * (accc[nt][r] - 2.0f * t * bsum[nt][r]);
        }
        int pos = ((qc ^ p) << 2) + qr;
        int pb  = p * 128;
        s_HG[pb + pos]      = pack2(t2[0], t2[1]);
        s_HG[pb + 64 + pos] = pack2(gg[0], gg[1]);
      }
    }
    __syncthreads();                // b2
  }
  phaseD();                         // epilogue D for the final pass

  // ---- final: wave reduce, one atomic per wave ----
#pragma unroll
  for (int off = 32; off > 0; off >>= 1)
    wsum += __shfl_down(wsum, off, 64);
  if (l == 0)
    atomicAdd(out, wsum * (1.0f / ((float)NPTS * (float)(FCH - 1))));
}

extern "C" void kernel_launch(void* const* d_in, const int* in_sizes, int n_in,
                              void* d_out, int out_size, void* d_ws, size_t ws_size,
                              hipStream_t stream) {
  const float* x     = (const float*)d_in[0];
  const float* omega = (const float*)d_in[1];
  const float* W1    = (const float*)d_in[2];
  const float* b1    = (const float*)d_in[3];
  const float* W2    = (const float*)d_in[4];
  const float* b2    = (const float*)d_in[5];
  const float* W3    = (const float*)d_in[6];
  const float* b3    = (const float*)d_in[7];
  float* out = (float*)d_out;

  (void)hipMemsetAsync(out, 0, sizeof(float), stream);
  helmholtz_kernel<<<GRID, BLOCK, 0, stream>>>(x, omega, W1, b1, W2, b2, W3, b3, out);
}

// Round 13
// 127.436 us; speedup vs baseline: 1.4442x; 1.4442x over previous
//
#include <hip/hip_runtime.h>
#include <math.h>

#ifndef __has_builtin
#define __has_builtin(x) 0
#endif

#define NPTS   131072
#define FCH    16
#define CSND   343.0f
#define PB     64           // points per pass (doubled)
#define BLOCK  512          // 8 waves
#define GRID   256          // 1 WG/CU, persistent; exactly 8 passes/WG
#define NBLK   (NPTS / PB)  // 2048

typedef _Float16 half8 __attribute__((ext_vector_type(8)));
typedef _Float16 half2v __attribute__((ext_vector_type(2)));
typedef float    f32x4 __attribute__((ext_vector_type(4)));

static __device__ __forceinline__ half2v pk2h(float a, float b) {
#if __has_builtin(__builtin_amdgcn_cvt_pkrtz)
  return __builtin_bit_cast(half2v, __builtin_amdgcn_cvt_pkrtz(a, b));
#else
  half2v v; v[0] = (_Float16)a; v[1] = (_Float16)b;
  return v;
#endif
}
static __device__ __forceinline__ unsigned pack2(float a, float b) {
  return __builtin_bit_cast(unsigned, pk2h(a, b));
}
#define U32(h) __builtin_bit_cast(unsigned, (h))

// tanh(x) = 1 - 2/(e^{2x}+1): exp+rcp on trans pipe, monotone at +/-inf.
static __device__ __forceinline__ float mytanh(float x) {
#if __has_builtin(__builtin_amdgcn_exp2f)
  float e = __builtin_amdgcn_exp2f(2.885390082f * x);   // 2*log2(e)*x
#else
  float e = __expf(2.0f * x);
#endif
  return fmaf(-2.0f, __builtin_amdgcn_rcpf(e + 1.0f), 1.0f);
}

// BARRIER-EVENT MINIMIZATION. Cross-round law (R3..R12): dur orders by
// barrier events/CU (= WG-passes/CU x barriers/pass), NOT occupancy:
//   32 events: R6=59.4, R9=56.5.  64 events: R11=70, R3/R8=78, R7=92, R12=120.
// Each event costs ~2.9k cycles of unfilled drain (R6: 8.9k cyc/pass vs ~3k
// pipe work); co-resident WGs never fill it (occupancy 14-35% all slower).
// => Halve events to 16: PB=64, BLOCK=512 (8 waves), GRID=256 (1 WG/CU,
// exactly 8 passes), R6's proven 2-barrier skeleton, single-buffered.
// LDS 112 KB (< 128 KB proven on gfx950): s_A 80 KB + s_HG 32 KB.
// 8 waves = 2/SIMD (R9's effective TLP); all phases 8-way balanced:
//   A: thread = 2 points (pA2, pA2+32) x units 8g..8g+7; packed-f16.
//   B: wave (mq=w>>1, nh=w&1): m-quarter 16mq..+15 x n-half 64nh..+63;
//      w2f[4][4]; per-d accd collapse; 28 ds_read + 80 MFMA per wave.
//   C: wave's (point,col) outputs -> HG, q = 32nh+16pr+col, key p&15.
//   D: wave = (ph2=w>>1 m-tile, nh re/im); 8 MFMA; w3f j-permuted.
// LDS maps (all swizzle keys reduce to the R6 forms since tiles are 16-mult):
//   s_A[320][64] dw: rows R = v*64+p (v=0..4: h1,d0,d1,d2,c1; p=0..63),
//     chunk c at (c ^ (R&15)), R&15 = p&15.
//   s_HG[64][128] dw: point p: h2 [p*128..+63], G [+64..+127]; dword
//     q = 32nh+16pr+col at chunk ((q>>2) ^ (p&15)); w3f rows j-permuted.
// Loop: [D(i-1); A(i)] |b1| [loadX(i+1); B(i); C(i)] |b2|  (R6 hazards).
// Register body == R6 (~124); (512,1) leaves allocator unconstrained.

__global__ __launch_bounds__(BLOCK, 1) void helmholtz_kernel(
    const float* __restrict__ x,      // [N,3]
    const float* __restrict__ omega,  // [16]
    const float* __restrict__ W1,     // [3,128]
    const float* __restrict__ b1,     // [128]
    const float* __restrict__ W2,     // [128,128]
    const float* __restrict__ b2,     // [128]
    const float* __restrict__ W3,     // [128,32]
    const float* __restrict__ b3,     // [32]
    float* __restrict__ out)
{
  __shared__ unsigned s_A[320 * 64];   // 80 KB
  __shared__ unsigned s_HG[64 * 128];  // 32 KB  (112 KB total -> 1 WG/CU)

  const int tid  = threadIdx.x;
  const int w    = tid >> 6;   // wave 0..7
  const int l    = tid & 63;
  const int col  = l & 15;
  const int quad = l >> 4;
  const int mq   = w >> 1;     // B m-quarter; D m-tile
  const int nh   = w & 1;      // B n-half; D re/im tile

  // ---- phase A task: points pA2, pA2+32; units 8g..8g+7 ----
  const int pA2 = tid >> 4;    // 0..31
  const int g   = tid & 15;
  float wx[8], wy[8], wz[8], bB[8];
#pragma unroll
  for (int u = 0; u < 8; u++) {
    int unit = 8 * g + u;
    wx[u] = W1[unit]; wy[u] = W1[128 + unit]; wz[u] = W1[256 + unit];
    bB[u] = b1[unit];
  }
  // packed W1 copies + folded -2*wq (computed once)
  half2v wxp[4], wyp[4], wzp[4], wqm[4];
#pragma unroll
  for (int j = 0; j < 4; j++) {
    wxp[j] = pk2h(wx[2*j], wx[2*j+1]);
    wyp[j] = pk2h(wy[2*j], wy[2*j+1]);
    wzp[j] = pk2h(wz[2*j], wz[2*j+1]);
    float wq0 = fmaf(wx[2*j],   wx[2*j],   fmaf(wy[2*j],   wy[2*j],   wz[2*j]   * wz[2*j]));
    float wq1 = fmaf(wx[2*j+1], wx[2*j+1], fmaf(wy[2*j+1], wy[2*j+1], wz[2*j+1] * wz[2*j+1]));
    wqm[j] = pk2h(-2.0f * wq0, -2.0f * wq1);
  }
  const half2v hone = {(_Float16)1.0f, (_Float16)1.0f};

  // ---- W2^T fragments: 4 n-tiles (cols 64*nh + 16*t4 + col), 64 VGPRs ----
  half8 w2f[4][4];
#pragma unroll
  for (int t4 = 0; t4 < 4; t4++) {
    const int n = 64 * nh + 16 * t4 + col;
#pragma unroll
    for (int ks = 0; ks < 4; ks++) {
      half8 f;
#pragma unroll
      for (int j8 = 0; j8 < 8; j8++)
        f[j8] = (_Float16)W2[(ks * 32 + (quad << 3) + j8) * 128 + n];
      w2f[t4][ks] = f;
    }
  }
  // ---- W3^T fragment, j-permuted to match HG layout (16 VGPRs) ----
  half8 w3f[4];
#pragma unroll
  for (int ks = 0; ks < 4; ks++) {
    half8 f;
#pragma unroll
    for (int j8 = 0; j8 < 8; j8++) {
      int kap = ks * 32 + (quad << 3) + j8;
      int q   = kap >> 1;
      int j   = 64 * (q >> 5) + 32 * ((q >> 4) & 1) + 16 * (kap & 1) + (q & 15);
      f[j8] = (_Float16)W3[j * 32 + 16 * nh + col];
    }
    w3f[ks] = f;
  }

  float b2r[4];
#pragma unroll
  for (int t4 = 0; t4 < 4; t4++) b2r[t4] = b2[64 * nh + 16 * t4 + col];
  float k2v = 0.0f;
  if (col >= 1) {
    float om = omega[col] * (1.0f / CSND);
    k2v = om * om;
  }
  const float b3v = b3[16 * nh + col];

  float wsum = 0.0f;
  float xr[2][3];

  auto loadX = [&](int blk) {
    const float* xb = x + (size_t)blk * PB * 3;
#pragma unroll
    for (int hp = 0; hp < 2; hp++) {
      int p = pA2 + 32 * hp;
      xr[hp][0] = xb[3 * p]; xr[hp][1] = xb[3 * p + 1]; xr[hp][2] = xb[3 * p + 2];
    }
  };

  auto phaseA = [&]() {
    const int cbase = (g ^ (pA2 & 15)) << 2;
#pragma unroll
    for (int hp = 0; hp < 2; hp++) {
      int p = pA2 + 32 * hp;
      float x0 = xr[hp][0], x1 = xr[hp][1], x2 = xr[hp][2];
      float t[8];
#pragma unroll
      for (int u = 0; u < 8; u++) {
        float z = fmaf(x0, wx[u], fmaf(x1, wy[u], fmaf(x2, wz[u], bB[u])));
        t[u] = mytanh(z);
      }
      half2v tp[4], sp[4];
#pragma unroll
      for (int j = 0; j < 4; j++) {
        tp[j] = pk2h(t[2*j], t[2*j+1]);
        sp[j] = hone - tp[j] * tp[j];
      }
      uint4 q;
      q = make_uint4(U32(tp[0]), U32(tp[1]), U32(tp[2]), U32(tp[3]));
      *(uint4*)&s_A[(p)        * 64 + cbase] = q;
      q = make_uint4(U32(sp[0]*wxp[0]), U32(sp[1]*wxp[1]),
                     U32(sp[2]*wxp[2]), U32(sp[3]*wxp[3]));
      *(uint4*)&s_A[(64 + p)   * 64 + cbase] = q;
      q = make_uint4(U32(sp[0]*wyp[0]), U32(sp[1]*wyp[1]),
                     U32(sp[2]*wyp[2]), U32(sp[3]*wyp[3]));
      *(uint4*)&s_A[(128 + p)  * 64 + cbase] = q;
      q = make_uint4(U32(sp[0]*wzp[0]), U32(sp[1]*wzp[1]),
                     U32(sp[2]*wzp[2]), U32(sp[3]*wzp[3]));
      *(uint4*)&s_A[(192 + p)  * 64 + cbase] = q;
      half2v cp[4];
#pragma unroll
      for (int j = 0; j < 4; j++) cp[j] = (tp[j] * sp[j]) * wqm[j];
      q = make_uint4(U32(cp[0]), U32(cp[1]), U32(cp[2]), U32(cp[3]));
      *(uint4*)&s_A[(256 + p)  * 64 + cbase] = q;
    }
  };

  auto phaseDE = [&]() {
    const int pbase = (16 * mq + col) * 128;   // point row; key (p&15)=col
    f32x4 dy = (f32x4){0.0f, 0.0f, 0.0f, 0.0f};
    f32x4 dl = (f32x4){0.0f, 0.0f, 0.0f, 0.0f};
#pragma unroll
    for (int ks = 0; ks < 4; ks++) {
      int pos = ((((ks << 2) + quad) ^ col) << 2);
      half8 afy = *(const half8*)&s_HG[pbase + pos];
      half8 afl = *(const half8*)&s_HG[pbase + 64 + pos];
      dy = __builtin_amdgcn_mfma_f32_16x16x32_f16(afy, w3f[ks], dy, 0, 0, 0);
      dl = __builtin_amdgcn_mfma_f32_16x16x32_f16(afl, w3f[ks], dl, 0, 0, 0);
    }
    if (col >= 1) {
#pragma unroll
      for (int r = 0; r < 4; r++) {
        float yv  = dy[r] + b3v;
        float res = fmaf(k2v, yv, dl[r]);
        wsum += res * res;
      }
    }
  };

  // ---- main loop: [D(i-1); A(i)] |b1| [loadX; B(i); C(i)] |b2| ----
  loadX(blockIdx.x);
  bool first = true;
  for (int blk = blockIdx.x; blk < NBLK; blk += GRID) {
    if (!first) phaseDE();          // D(i-1): reads s_HG
    first = false;
    phaseA();                       // A(i): writes s_A
    __syncthreads();                // b1

    int nblk = blk + GRID;
    if (nblk < NBLK) loadX(nblk);   // prefetch x for next pass

    // ---- B(i): m-quarter x n-half GEMM; per-d collapse caps transients ----
    f32x4 bsum[4], acch[4], accc[4];
#pragma unroll
    for (int t4 = 0; t4 < 4; t4++)
      bsum[t4] = (f32x4){0.0f, 0.0f, 0.0f, 0.0f};
#pragma unroll
    for (int d = 0; d < 3; d++) {
      f32x4 accd[4];
#pragma unroll
      for (int t4 = 0; t4 < 4; t4++)
        accd[t4] = (f32x4){0.0f, 0.0f, 0.0f, 0.0f};
      const int rb = ((d + 1) * 64 + 16 * mq + col) * 64;
#pragma unroll
      for (int ks = 0; ks < 4; ks++) {
        half8 af = *(const half8*)&s_A[rb + ((((ks << 2) + quad) ^ col) << 2)];
        accd[0] = __builtin_amdgcn_mfma_f32_16x16x32_f16(af, w2f[0][ks], accd[0], 0, 0, 0);
        accd[1] = __builtin_amdgcn_mfma_f32_16x16x32_f16(af, w2f[1][ks], accd[1], 0, 0, 0);
        accd[2] = __builtin_amdgcn_mfma_f32_16x16x32_f16(af, w2f[2][ks], accd[2], 0, 0, 0);
        accd[3] = __builtin_amdgcn_mfma_f32_16x16x32_f16(af, w2f[3][ks], accd[3], 0, 0, 0);
      }
#pragma unroll
      for (int t4 = 0; t4 < 4; t4++)
        bsum[t4] += accd[t4] * accd[t4];
    }
#pragma unroll
    for (int t4 = 0; t4 < 4; t4++) {
      acch[t4] = (f32x4){0.0f, 0.0f, 0.0f, 0.0f};
      accc[t4] = (f32x4){0.0f, 0.0f, 0.0f, 0.0f};
    }
    {
      const int rb0 = (16 * mq + col) * 64;          // h1 rows (v=0)
      const int rb4 = (256 + 16 * mq + col) * 64;    // c1 rows (v=4)
#pragma unroll
      for (int ks = 0; ks < 4; ks++) {
        int pos = ((((ks << 2) + quad) ^ col) << 2);
        half8 afh = *(const half8*)&s_A[rb0 + pos];
        half8 afc = *(const half8*)&s_A[rb4 + pos];
        acch[0] = __builtin_amdgcn_mfma_f32_16x16x32_f16(afh, w2f[0][ks], acch[0], 0, 0, 0);
        acch[1] = __builtin_amdgcn_mfma_f32_16x16x32_f16(afh, w2f[1][ks], acch[1], 0, 0, 0);
        acch[2] = __builtin_amdgcn_mfma_f32_16x16x32_f16(afh, w2f[2][ks], acch[2], 0, 0, 0);
        acch[3] = __builtin_amdgcn_mfma_f32_16x16x32_f16(afh, w2f[3][ks], acch[3], 0, 0, 0);
        accc[0] = __builtin_amdgcn_mfma_f32_16x16x32_f16(afc, w2f[0][ks], accc[0], 0, 0, 0);
        accc[1] = __builtin_amdgcn_mfma_f32_16x16x32_f16(afc, w2f[1][ks], accc[1], 0, 0, 0);
        accc[2] = __builtin_amdgcn_mfma_f32_16x16x32_f16(afc, w2f[2][ks], accc[2], 0, 0, 0);
        accc[3] = __builtin_amdgcn_mfma_f32_16x16x32_f16(afc, w2f[3][ks], accc[3], 0, 0, 0);
      }
    }

    // ---- C(i): layer-2 elementwise; paired-dword writes into s_HG ----
#pragma unroll
    for (int r = 0; r < 4; r++) {
      int p = 16 * mq + (quad << 2) + r;     // point 0..63
      float t2[4], gg[4];
#pragma unroll
      for (int t4 = 0; t4 < 4; t4++) {
        float z2 = acch[t4][r] + b2r[t4];
        float t  = mytanh(z2);
        float s2 = 1.0f - t * t;
        t2[t4] = t;
        gg[t4] = s2 * (accc[t4][r] - 2.0f * t * bsum[t4][r]);
      }
      int pb = p * 128;
#pragma unroll
      for (int pr = 0; pr < 2; pr++) {
        int q   = 32 * nh + 16 * pr + col;
        int pos = (((q >> 2) ^ (p & 15)) << 2) + (q & 3);
        s_HG[pb + pos]      = pack2(t2[2 * pr], t2[2 * pr + 1]);
        s_HG[pb + 64 + pos] = pack2(gg[2 * pr], gg[2 * pr + 1]);
      }
    }
    __syncthreads();                // b2
  }
  phaseDE();                        // epilogue D for the final pass

  // ---- final: wave reduce, one atomic per wave ----
#pragma unroll
  for (int off = 32; off > 0; off >>= 1)
    wsum += __shfl_down(wsum, off, 64);
  if (l == 0)
    atomicAdd(out, wsum * (1.0f / ((float)NPTS * (float)(FCH - 1))));
}

extern "C" void kernel_launch(void* const* d_in, const int* in_sizes, int n_in,
                              void* d_out, int out_size, void* d_ws, size_t ws_size,
                              hipStream_t stream) {
  const float* x     = (const float*)d_in[0];
  const float* omega = (const float*)d_in[1];
  const float* W1    = (const float*)d_in[2];
  const float* b1    = (const float*)d_in[3];
  const float* W2    = (const float*)d_in[4];
  const float* b2    = (const float*)d_in[5];
  const float* W3    = (const float*)d_in[6];
  const float* b3    = (const float*)d_in[7];
  float* out = (float*)d_out;

  (void)hipMemsetAsync(out, 0, sizeof(float), stream);
  helmholtz_kernel<<<GRID, BLOCK, 0, stream>>>(x, omega, W1, b1, W2, b2, W3, b3, out);
}